// Round 6
// baseline (331.978 us; speedup 1.0000x reference)
//
#include <hip/hip_runtime.h>
#include <stdint.h>

typedef __attribute__((ext_vector_type(8))) short bf16x8;   // 8 bf16 raw bits (4 VGPRs)
typedef __attribute__((ext_vector_type(4))) float f32x4;    // MFMA accumulator / vec load

static __device__ __forceinline__ uint16_t f2bf(float f) {
    uint32_t u;
    __builtin_memcpy(&u, &f, 4);
    return (uint16_t)((u + 0x7FFFu + ((u >> 16) & 1u)) >> 16);   // RNE
}

// ---------------------------------------------------------------------------
// K12: fused solve + M construction. 2 blocks x 128 threads.
// Phase 1 (solve): X = (I-A)^-1 B forward substitution. Block b owns columns
// [64b,64b+64); lane dl's x column lives in LDS row xT[dl][*], quad-XOR
// swizzled (word = dl*128 + (t ^ ((dl&7)<<2))) -> per-lane ds_read_b128 over
// t puts the 8 lane-groups on 8 disjoint bank-quads.
// Round-5 k1 still serialized ~2030 quad-iters on the x write->read alias
// (compiler can't hoist reads of old x past the per-step x write). Fix: per
// 16-row panel, a PARALLEL prologue accumulates base[i] = sum_{t<16p} A.x
// (reads only old x -> no alias -> issue-bound), then the serial 16 steps
// touch only the current panel's <=3 quads (short dependence chain).
// base[16] indexed only from fully-unrolled loops (static -> registers).
// Phase 2 (k2 fused): M[o][d] = sum_s C[o][s]*x[s][d] + D[o][d], using xT
// straight from LDS (X never goes to global). C staged in the dead A-panel.
// Written in MFMA 16x16x32 fragment order (verified formula from k2):
//   lane = ((d>>3)&3)*16 + (o&15); j = d&7; f = (o>>4)*4 + (d>>5)
//   index = (f*64+lane)*8 + j
// ---------------------------------------------------------------------------
__global__ __launch_bounds__(128) void k12_solve_makeM(const float* __restrict__ Ag,
                                                       const float* __restrict__ Bg,
                                                       const float* __restrict__ Cg,
                                                       const float* __restrict__ Dg,
                                                       uint16_t* __restrict__ Mfrag) {
    __shared__ float Ap[16 * 128];   // 8 KB: A panel (phase 1), C panel (phase 2)
    __shared__ float Bp[16 * 64];    // 4 KB: B panel
    __shared__ float xT[64 * 128];   // 32 KB: x transposed per-lane, quad-swizzled

    const int tid = threadIdx.x;              // 0..127
    const int dl  = tid & 63;                 // local column
    const int d   = blockIdx.x * 64 + dl;     // global column
    const int sw  = (dl & 7) << 2;            // quad swizzle (word units)
    float* xrow = &xT[dl * 128];

    // ---- Phase 1: panel-blocked forward substitution (wave 0 solves) ----
    for (int p = 0; p < 8; ++p) {
        __syncthreads();   // previous panel's reads complete before overwrite
        {
            // A rows [16p,16p+16): 512 f32x4, 4 per thread (128 threads).
            const f32x4* src = reinterpret_cast<const f32x4*>(Ag + p * 2048);
            f32x4* dst = reinterpret_cast<f32x4*>(Ap);
#pragma unroll
            for (int i = 0; i < 4; ++i) dst[i * 128 + tid] = src[i * 128 + tid];
            // B rows [16p,16p+16) for this block's 64 columns: 1024 words.
#pragma unroll
            for (int w = 0; w < 8; ++w) {
                int idx = w * 128 + tid;
                int row = idx >> 6, col = idx & 63;
                Bp[idx] = Bg[(p * 16 + row) * 128 + blockIdx.x * 64 + col];
            }
        }
        __syncthreads();

        if (tid < 64) {
            // Prologue: contributions of x[0..16p) to all 16 panel rows.
            // Reads only already-final x -> 16 independent fma chains, no
            // write->read alias -> full ILP.
            float base[16];
#pragma unroll
            for (int i = 0; i < 16; ++i) base[i] = 0.f;
            for (int q = 0; q < 4 * p; ++q) {
                f32x4 xv = *reinterpret_cast<const f32x4*>(xrow + ((q * 4) ^ sw));
#pragma unroll
                for (int i = 0; i < 16; ++i) {
                    f32x4 av = *reinterpret_cast<const f32x4*>(Ap + i * 128 + q * 4);
                    base[i] += av[0] * xv[0] + av[1] * xv[1] + av[2] * xv[2] + av[3] * xv[3];
                }
            }
            // Serial 16 steps: only current-panel terms t in [16p, s).
            const int t0 = p * 16;
#pragma unroll
            for (int sl = 0; sl < 16; ++sl) {
                const int s = t0 + sl;
                const float* Ar = Ap + sl * 128;
                float acc = base[sl];
#pragma unroll
                for (int qq = 0; qq < (sl >> 2); ++qq) {
                    int tq = t0 + qq * 4;
                    f32x4 av = *reinterpret_cast<const f32x4*>(Ar + tq);
                    f32x4 xv = *reinterpret_cast<const f32x4*>(xrow + (tq ^ sw));
                    acc += av[0] * xv[0] + av[1] * xv[1] + av[2] * xv[2] + av[3] * xv[3];
                }
#pragma unroll
                for (int k = 0; k < (sl & 3); ++k) {
                    int t = t0 + (sl & ~3) + k;
                    acc += Ar[t] * xrow[t ^ sw];
                }
                float xs = (Bp[sl * 64 + dl] + acc) / (1.0f - Ar[s]);
                xrow[s ^ sw] = xs;   // own-lane LDS write (RAW via lgkmcnt)
            }
        }
    }

    // ---- Phase 2: M = C*X + D for this block's 64 columns ----
    const int oh = tid >> 6;   // wave id = o-half (wave-uniform)
    for (int ot = 0; ot < 8; ++ot) {
        __syncthreads();   // also covers xT final writes on first iteration
        // Stage 16 C rows (8 for each o-half): 2048 words, 16 per thread.
        for (int w = tid; w < 2048; w += 128) {
            int rr = w >> 7;          // 0..15
            int cc = w & 127;
            int o  = (rr >> 3) * 64 + ot * 8 + (rr & 7);
            Ap[w] = Cg[o * 128 + cc];
        }
        __syncthreads();
        float macc[8];
#pragma unroll
        for (int r = 0; r < 8; ++r) macc[r] = 0.f;
        const float* Crow = Ap + oh * (8 * 128);   // wave-uniform -> LDS broadcast
        for (int q = 0; q < 32; ++q) {
            f32x4 xv = *reinterpret_cast<const f32x4*>(xrow + ((q * 4) ^ sw));
#pragma unroll
            for (int r = 0; r < 8; ++r) {
                f32x4 cv = *reinterpret_cast<const f32x4*>(Crow + r * 128 + q * 4);
                macc[r] += cv[0] * xv[0] + cv[1] * xv[1] + cv[2] * xv[2] + cv[3] * xv[3];
            }
        }
#pragma unroll
        for (int r = 0; r < 8; ++r) {
            const int o = oh * 64 + ot * 8 + r;
            float m = macc[r] + Dg[o * 128 + d];
            const int c = o >> 4, n = o & 15;
            const int t = d >> 5, r2 = d & 31;
            const int half = r2 >> 3, j = r2 & 7;
            const int lane = half * 16 + n;
            const int f = c * 4 + t;
            Mfrag[(f * 64 + lane) * 8 + j] = f2bf(m);
        }
    }
}

// ---------------------------------------------------------------------------
// K3: y = u @ M^T. 262144 rows, K=128, N=128. Grid 1024 x 256 thr; each wave
// now owns 4 consecutive 16-row tiles, software-pipelined: pack tile t out of
// the load buffer -> issue tile t+1's 8 dwordx4 loads -> 32 MFMAs -> stores.
// Round-5 evidence: one-shot waves = 83.5us at 2.4 TB/s, VALUBusy 4.3%,
// Occ 30% (pure load-latency stall, BW floor ~31-42us). Loads now fly under
// ~600cy of MFMA+store per tile. Single buffer (pack frees it before the
// re-issue) keeps VGPR ~100 <= 128 so 4 blocks/CU is preserved.
// MFMA operands swapped: acc = mfma(M, u) -> lane's 4 acc regs are 4
// consecutive output columns of one row -> global_store_dwordx4 (verified
// round 5, absmax 0.00390625).
// ---------------------------------------------------------------------------
__global__ __launch_bounds__(256, 4) void k3_gemm(const float* __restrict__ U,
                                                  const uint16_t* __restrict__ Mfrag,
                                                  float* __restrict__ Y) {
    __shared__ uint16_t Msh[16384];   // 32 KB: 32 frags x 64 lanes x 8 bf16
    {
        const uint4* src = reinterpret_cast<const uint4*>(Mfrag);
        uint4* dst = reinterpret_cast<uint4*>(Msh);
#pragma unroll
        for (int i = 0; i < 8; ++i)
            dst[threadIdx.x + 256 * i] = src[threadIdx.x + 256 * i];
    }
    __syncthreads();

    const int lane = threadIdx.x & 63;
    const int wid  = threadIdx.x >> 6;
    const int urow = lane & 15;   // u row within tile (B-operand n index)
    const int kh   = lane >> 4;   // k-octet (0..3), 8 contiguous k each

    const size_t wrow = (size_t)blockIdx.x * 256 + (size_t)wid * 64;  // wave's rows
    const float* up = U + (wrow + urow) * 128 + kh * 8;

    f32x4 buf[8];
#pragma unroll
    for (int t = 0; t < 4; ++t) {
        buf[2 * t]     = *reinterpret_cast<const f32x4*>(up + t * 32);
        buf[2 * t + 1] = *reinterpret_cast<const f32x4*>(up + t * 32 + 4);
    }

#pragma unroll
    for (int it = 0; it < 4; ++it) {
        // pack current tile (waits the loads, then buf regs are free)
        bf16x8 Afr[4];
#pragma unroll
        for (int t = 0; t < 4; ++t) {
            f32x4 lo = buf[2 * t], hi = buf[2 * t + 1];
            bf16x8 a;
#pragma unroll
            for (int j = 0; j < 4; ++j) {
                a[j]     = (short)f2bf(lo[j]);
                a[4 + j] = (short)f2bf(hi[j]);
            }
            Afr[t] = a;
        }
        // prefetch next tile: in flight during the MFMAs + stores below
        if (it < 3) {
            const float* upn = up + (size_t)(it + 1) * 16 * 128;
#pragma unroll
            for (int t = 0; t < 4; ++t) {
                buf[2 * t]     = *reinterpret_cast<const f32x4*>(upn + t * 32);
                buf[2 * t + 1] = *reinterpret_cast<const f32x4*>(upn + t * 32 + 4);
            }
        }
        f32x4 acc[8] = {};
#pragma unroll
        for (int c = 0; c < 8; ++c)
#pragma unroll
            for (int t = 0; t < 4; ++t) {
                bf16x8 b = *reinterpret_cast<const bf16x8*>(Msh + ((c * 4 + t) * 64 + lane) * 8);
                acc[c] = __builtin_amdgcn_mfma_f32_16x16x32_bf16(b, Afr[t], acc[c], 0, 0, 0);
            }
        float* yp = Y + (wrow + it * 16 + urow) * 128 + kh * 4;
#pragma unroll
        for (int c = 0; c < 8; ++c)
            *reinterpret_cast<f32x4*>(yp + c * 16) = acc[c];
    }
}

// ---------------------------------------------------------------------------
extern "C" void kernel_launch(void* const* d_in, const int* in_sizes, int n_in,
                              void* d_out, int out_size, void* d_ws, size_t ws_size,
                              hipStream_t stream) {
    const float* u = (const float*)d_in[0];   // [32, 8192, 128] fp32
    const float* A = (const float*)d_in[1];   // [128, 128] fp32, lower-tri
    const float* B = (const float*)d_in[2];   // [128, 128] fp32
    const float* C = (const float*)d_in[3];   // [128, 128] fp32
    const float* D = (const float*)d_in[4];   // [128, 128] fp32

    uint16_t* Mfrag = (uint16_t*)d_ws;        // 32 KB bf16 frag order (X never hits global)
    float*    Y     = (float*)d_out;          // [32*8192, 128] fp32

    hipLaunchKernelGGL(k12_solve_makeM, dim3(2),    dim3(128), 0, stream, A, B, C, D, Mfrag);
    hipLaunchKernelGGL(k3_gemm,         dim3(1024), dim3(256), 0, stream, u, Mfrag, Y);
}

// Round 8
// 325.636 us; speedup vs baseline: 1.0195x; 1.0195x over previous
//
#include <hip/hip_runtime.h>
#include <stdint.h>

typedef __attribute__((ext_vector_type(8))) short bf16x8;   // 8 bf16 raw bits (4 VGPRs)
typedef __attribute__((ext_vector_type(4))) float f32x4;    // MFMA accumulator / vec load

static __device__ __forceinline__ uint16_t f2bf(float f) {
    uint32_t u;
    __builtin_memcpy(&u, &f, 4);
    return (uint16_t)((u + 0x7FFFu + ((u >> 16) & 1u)) >> 16);   // RNE
}

// ---------------------------------------------------------------------------
// K12 v2: fused solve + M construction. 2 blocks x 256 threads (4 waves).
// Round-6 evidence: v1 = 91us, VALUBusy 0.127% (1 wave solving, serial
// 16-step tails on the ~120cy LDS write->read chain, LDS-staged C with 16
// barriers). v2 removes every serial structure except an 8-step panel chain:
//   - W_p = (I - A_pp)^{-1} precomputed for the 8 diagonal 16x16 blocks,
//     one column per thread (128-way parallel, static-index unrolled).
//   - Step p: S_p = B_p + A[rows,0:16p]*X  (4 waves x 4 rows, A-row
//     addresses wave-uniform -> scalar loads, x quads from LDS)
//     ... barrier ... X_p = W_p*S_p (each output row fully parallel, W
//     broadcast from LDS) ... barrier. 2 barriers/step, 8 steps.
//   - x per-column in LDS, quad-XOR swizzle word = dl*128+(t^((dl&7)<<2))
//     (8 lane-groups on 8 disjoint bank-quads for per-lane ds_read_b128).
// Phase 2: M[o][d] = sum C[o][s] x[s][d] + D[o][d]; wave w owns o in
// [32w,32w+32): C addresses wave-uniform (readfirstlane) -> scalar-load path,
// no LDS staging, no barriers; 32 accumulators static-indexed.
// M written in MFMA 16x16x32 fragment order (formula harness-verified):
//   lane = ((d>>3)&3)*16 + (o&15); j = d&7; f = (o>>4)*4 + (d>>5)
//   index = (f*64+lane)*8 + j
// ---------------------------------------------------------------------------
__global__ __launch_bounds__(256) void k12_solve_makeM(const float* __restrict__ Ag,
                                                       const float* __restrict__ Bg,
                                                       const float* __restrict__ Cg,
                                                       const float* __restrict__ Dg,
                                                       uint16_t* __restrict__ Mfrag) {
    __shared__ float xT[64 * 128];   // 32 KB: x transposed per-lane, quad-swizzled
    __shared__ float Ad[8 * 256];    // 8 KB: the 8 diagonal 16x16 blocks of A
    __shared__ float Wb[8 * 256];    // 8 KB: W_p = (I-A_pp)^-1, [p][row][col]
    __shared__ float Sb[16 * 64];    // 4 KB: current panel S

    const int tid = threadIdx.x;               // 0..255
    const int dl  = tid & 63;                  // local column
    const int d   = blockIdx.x * 64 + dl;      // global column
    const int wu  = __builtin_amdgcn_readfirstlane(tid >> 6);   // wave id 0..3 (SGPR)
    const int sw  = (dl & 7) << 2;             // quad swizzle (word units)
    float* xrow = &xT[dl * 128];

    // ---- Stage the 8 diagonal 16x16 blocks of A (2048 words, 8/thread) ----
#pragma unroll
    for (int t = 0; t < 8; ++t) {
        int idx = t * 256 + tid;
        int p = idx >> 8, i = (idx >> 4) & 15, j = idx & 15;
        Ad[idx] = Ag[(p * 16 + i) * 128 + p * 16 + j];
    }
    __syncthreads();

    // ---- W_p columns: thread (p=tid>>4, j=tid&15) forward-substitutes e_j.
    // All loops fully unrolled: w[] statically indexed (registers). w[i]=0 for
    // i<j falls out by induction (s starts 0, all prior w are 0).
    if (tid < 128) {
        const int p = tid >> 4, j = tid & 15;
        const float* App = Ad + p * 256;
        float rd[16];
#pragma unroll
        for (int i = 0; i < 16; ++i) rd[i] = 1.0f / (1.0f - App[i * 16 + i]);
        float w[16];
#pragma unroll
        for (int i = 0; i < 16; ++i) {
            float s = (i == j) ? 1.0f : 0.0f;
#pragma unroll
            for (int t = 0; t < i; ++t) s += App[i * 16 + t] * w[t];
            w[i] = s * rd[i];
        }
#pragma unroll
        for (int i = 0; i < 16; ++i) Wb[p * 256 + i * 16 + j] = w[i];
    }
    __syncthreads();

    // ---- 8-step panel solve: X_p = W_p (B_p + A[rows,0:16p] X_prefix) ----
    for (int p = 0; p < 8; ++p) {
        // B for this wave's 4 rows (issued early; coalesced per row).
        float bx0 = Bg[(p * 16 + wu     ) * 128 + d];
        float bx1 = Bg[(p * 16 + wu +  4) * 128 + d];
        float bx2 = Bg[(p * 16 + wu +  8) * 128 + d];
        float bx3 = Bg[(p * 16 + wu + 12) * 128 + d];

        // Update: acc_k = sum_{t<16p} A[16p+wu+4k][t] * x[t].
        // A addresses wave-uniform (scalar path); x quads per-lane from LDS.
        const float* Ar = Ag + (p * 16 + wu) * 128;
        float a0 = 0.f, a1 = 0.f, a2 = 0.f, a3 = 0.f;
#pragma unroll 2
        for (int qp = 0; qp < p; ++qp) {
#pragma unroll
            for (int qq = 0; qq < 4; ++qq) {
                const int t0 = qp * 16 + qq * 4;
                f32x4 xv = *reinterpret_cast<const f32x4*>(xrow + (t0 ^ sw));
                f32x4 v0 = *reinterpret_cast<const f32x4*>(Ar + t0);
                f32x4 v1 = *reinterpret_cast<const f32x4*>(Ar + 4 * 128 + t0);
                f32x4 v2 = *reinterpret_cast<const f32x4*>(Ar + 8 * 128 + t0);
                f32x4 v3 = *reinterpret_cast<const f32x4*>(Ar + 12 * 128 + t0);
                a0 += v0[0] * xv[0] + v0[1] * xv[1] + v0[2] * xv[2] + v0[3] * xv[3];
                a1 += v1[0] * xv[0] + v1[1] * xv[1] + v1[2] * xv[2] + v1[3] * xv[3];
                a2 += v2[0] * xv[0] + v2[1] * xv[1] + v2[2] * xv[2] + v2[3] * xv[3];
                a3 += v3[0] * xv[0] + v3[1] * xv[1] + v3[2] * xv[2] + v3[3] * xv[3];
            }
        }
        Sb[(wu     ) * 64 + dl] = bx0 + a0;
        Sb[(wu +  4) * 64 + dl] = bx1 + a1;
        Sb[(wu +  8) * 64 + dl] = bx2 + a2;
        Sb[(wu + 12) * 64 + dl] = bx3 + a3;
        __syncthreads();

        // Apply: X_p rows {wu,wu+4,wu+8,wu+12} = W_p rows . S (all 16 rows).
        float sv[16];
#pragma unroll
        for (int j = 0; j < 16; ++j) sv[j] = Sb[j * 64 + dl];   // conflict-free
#pragma unroll
        for (int k = 0; k < 4; ++k) {
            const int r = wu + 4 * k;
            const float* Wr = Wb + p * 256 + r * 16;   // wave-uniform: broadcast
            float xs = 0.f;
#pragma unroll
            for (int j4 = 0; j4 < 4; ++j4) {
                f32x4 wv = *reinterpret_cast<const f32x4*>(Wr + j4 * 4);
                xs += wv[0] * sv[4 * j4] + wv[1] * sv[4 * j4 + 1]
                    + wv[2] * sv[4 * j4 + 2] + wv[3] * sv[4 * j4 + 3];
            }
            xrow[(p * 16 + r) ^ sw] = xs;
        }
        __syncthreads();   // xT ready for next step's update / phase 2
    }

    // ---- Phase 2: M = C*X + D. Wave wu owns o in [32wu, 32wu+32). ----
    float macc[32];
#pragma unroll
    for (int oo = 0; oo < 32; ++oo) macc[oo] = 0.f;
    const float* Cbase = Cg + (size_t)wu * 32 * 128;   // wave-uniform base
    for (int q = 0; q < 32; ++q) {
        f32x4 xv = *reinterpret_cast<const f32x4*>(xrow + ((q * 4) ^ sw));
#pragma unroll
        for (int oo = 0; oo < 32; ++oo) {
            f32x4 cv = *reinterpret_cast<const f32x4*>(Cbase + oo * 128 + q * 4);
            macc[oo] += cv[0] * xv[0] + cv[1] * xv[1] + cv[2] * xv[2] + cv[3] * xv[3];
        }
    }
#pragma unroll
    for (int oo = 0; oo < 32; ++oo) {
        const int o = wu * 32 + oo;
        float m = macc[oo] + Dg[o * 128 + d];
        const int c = o >> 4, n = o & 15;
        const int t = d >> 5, r2 = d & 31;
        const int half = r2 >> 3, j = r2 & 7;
        const int lane = half * 16 + n;
        const int f = c * 4 + t;
        Mfrag[(f * 64 + lane) * 8 + j] = f2bf(m);
    }
}

// ---------------------------------------------------------------------------
// K3: y = u @ M^T. 262144 rows, K=128, N=128. Grid 1024 x 256 thr; each wave
// owns 4 consecutive 16-row tiles, software-pipelined: pack tile t out of
// the load buffer -> issue tile t+1's 8 dwordx4 loads -> 32 MFMAs -> stores.
// (Round-6: harness-verified, left the top-5.) MFMA operands swapped:
// acc = mfma(M, u) -> lane's 4 acc regs are 4 consecutive output columns of
// one row -> global_store_dwordx4. UNCHANGED from round 6.
// ---------------------------------------------------------------------------
__global__ __launch_bounds__(256, 4) void k3_gemm(const float* __restrict__ U,
                                                  const uint16_t* __restrict__ Mfrag,
                                                  float* __restrict__ Y) {
    __shared__ uint16_t Msh[16384];   // 32 KB: 32 frags x 64 lanes x 8 bf16
    {
        const uint4* src = reinterpret_cast<const uint4*>(Mfrag);
        uint4* dst = reinterpret_cast<uint4*>(Msh);
#pragma unroll
        for (int i = 0; i < 8; ++i)
            dst[threadIdx.x + 256 * i] = src[threadIdx.x + 256 * i];
    }
    __syncthreads();

    const int lane = threadIdx.x & 63;
    const int wid  = threadIdx.x >> 6;
    const int urow = lane & 15;   // u row within tile (B-operand n index)
    const int kh   = lane >> 4;   // k-octet (0..3), 8 contiguous k each

    const size_t wrow = (size_t)blockIdx.x * 256 + (size_t)wid * 64;  // wave's rows
    const float* up = U + (wrow + urow) * 128 + kh * 8;

    f32x4 buf[8];
#pragma unroll
    for (int t = 0; t < 4; ++t) {
        buf[2 * t]     = *reinterpret_cast<const f32x4*>(up + t * 32);
        buf[2 * t + 1] = *reinterpret_cast<const f32x4*>(up + t * 32 + 4);
    }

#pragma unroll
    for (int it = 0; it < 4; ++it) {
        // pack current tile (waits the loads, then buf regs are free)
        bf16x8 Afr[4];
#pragma unroll
        for (int t = 0; t < 4; ++t) {
            f32x4 lo = buf[2 * t], hi = buf[2 * t + 1];
            bf16x8 a;
#pragma unroll
            for (int j = 0; j < 4; ++j) {
                a[j]     = (short)f2bf(lo[j]);
                a[4 + j] = (short)f2bf(hi[j]);
            }
            Afr[t] = a;
        }
        // prefetch next tile: in flight during the MFMAs + stores below
        if (it < 3) {
            const float* upn = up + (size_t)(it + 1) * 16 * 128;
#pragma unroll
            for (int t = 0; t < 4; ++t) {
                buf[2 * t]     = *reinterpret_cast<const f32x4*>(upn + t * 32);
                buf[2 * t + 1] = *reinterpret_cast<const f32x4*>(upn + t * 32 + 4);
            }
        }
        f32x4 acc[8] = {};
#pragma unroll
        for (int c = 0; c < 8; ++c)
#pragma unroll
            for (int t = 0; t < 4; ++t) {
                bf16x8 b = *reinterpret_cast<const bf16x8*>(Msh + ((c * 4 + t) * 64 + lane) * 8);
                acc[c] = __builtin_amdgcn_mfma_f32_16x16x32_bf16(b, Afr[t], acc[c], 0, 0, 0);
            }
        float* yp = Y + (wrow + it * 16 + urow) * 128 + kh * 4;
#pragma unroll
        for (int c = 0; c < 8; ++c)
            *reinterpret_cast<f32x4*>(yp + c * 16) = acc[c];
    }
}

// ---------------------------------------------------------------------------
extern "C" void kernel_launch(void* const* d_in, const int* in_sizes, int n_in,
                              void* d_out, int out_size, void* d_ws, size_t ws_size,
                              hipStream_t stream) {
    const float* u = (const float*)d_in[0];   // [32, 8192, 128] fp32
    const float* A = (const float*)d_in[1];   // [128, 128] fp32, lower-tri
    const float* B = (const float*)d_in[2];   // [128, 128] fp32
    const float* C = (const float*)d_in[3];   // [128, 128] fp32
    const float* D = (const float*)d_in[4];   // [128, 128] fp32

    uint16_t* Mfrag = (uint16_t*)d_ws;        // 32 KB bf16 frag order (X never hits global)
    float*    Y     = (float*)d_out;          // [32*8192, 128] fp32

    hipLaunchKernelGGL(k12_solve_makeM, dim3(2),    dim3(256), 0, stream, A, B, C, D, Mfrag);
    hipLaunchKernelGGL(k3_gemm,         dim3(1024), dim3(256), 0, stream, u, Mfrag, Y);
}